// Round 2
// baseline (105.153 us; speedup 1.0000x reference)
//
#include <hip/hip_runtime.h>
#include <hip/hip_bf16.h>

// Problem constants: B=32, T=256, E=C=256, MIN_CONTEXT=64, FUTURE_STEPS=12
// S0 = 192 rows per batch, NROW = 32*192 = 6144, K = 256
// Tail region: t in [181,192) -> 11 singleton buckets; bucket0 = t<181.
// N_terms = sum_s 32*(192-s) = 71616.

#define NROW 6144
#define KDIM 256
#define TAIL0 181
#define NTERMS 71616.0f

typedef __attribute__((ext_vector_type(8))) short short8;
typedef __attribute__((ext_vector_type(4))) float f32x4;

__device__ inline ushort f2bf(float f) {
  union { float f; uint32_t u; } v; v.f = f;
  uint32_t u = v.u;
  return (ushort)((u + 0x7FFFu + ((u >> 16) & 1u)) >> 16);
}
__device__ inline float b2f(ushort h) {
  union { uint32_t u; float f; } v; v.u = ((uint32_t)h) << 16; return v.f;
}

// ---- A0: W (E,C) fp32 -> Wt (C,E) bf16 (transposed so B-frag reads contiguous K)
__global__ void k_castW(const float* __restrict__ W, ushort* __restrict__ Wt) {
  int c = blockIdx.x;      // 256
  int e = threadIdx.x;     // 256
  Wt[c * 256 + e] = f2bf(W[e * 256 + c]);
}

// ---- A1: contexts -> X bf16, t-major rows: X[t*32+j][k] = ctx[j][63+t][k]
__global__ void k_castX(const float* __restrict__ ctx, ushort* __restrict__ X) {
  int c = blockIdx.x;      // 6144
  int j = c & 31, t = c >> 5;
  const float4* src = (const float4*)(ctx + ((size_t)(j * 256 + 63 + t)) * 256);
  float4 f = src[threadIdx.x];       // 64 threads * 4 floats = 256
  ushort4 o;
  o.x = f2bf(f.x); o.y = f2bf(f.y); o.z = f2bf(f.z); o.w = f2bf(f.w);
  ((ushort4*)(X + (size_t)c * 256))[threadIdx.x] = o;
}

// ---- A2: P = emb_slice @ W, bf16 MFMA, one 16x16 frag per wave
__global__ void k_proj(const float* __restrict__ emb, const ushort* __restrict__ Wt,
                       ushort* __restrict__ P) {
  int w = threadIdx.x >> 6, l = threadIdx.x & 63;
  int gw = blockIdx.x * 4 + w;             // 6144 waves total
  int rt = gw >> 4, ct = gw & 15;          // 384 row tiles x 16 col tiles
  int row = rt * 16 + (l & 15);
  int b = row / 192, urow = row % 192;
  const float* ep = emb + ((size_t)(b * 256 + 64 + urow)) * 256;
  int kh = (l >> 4) * 8;
  const short8* wp = (const short8*)(Wt + (size_t)(ct * 16 + (l & 15)) * 256);
  f32x4 acc = {0.f, 0.f, 0.f, 0.f};
#pragma unroll
  for (int kk = 0; kk < 8; ++kk) {
    int k0 = kk * 32 + kh;
    float4 f0 = *(const float4*)(ep + k0);
    float4 f1 = *(const float4*)(ep + k0 + 4);
    short8 a;
    a[0] = (short)f2bf(f0.x); a[1] = (short)f2bf(f0.y);
    a[2] = (short)f2bf(f0.z); a[3] = (short)f2bf(f0.w);
    a[4] = (short)f2bf(f1.x); a[5] = (short)f2bf(f1.y);
    a[6] = (short)f2bf(f1.z); a[7] = (short)f2bf(f1.w);
    short8 bf = wp[k0 >> 3];
    acc = __builtin_amdgcn_mfma_f32_16x16x32_bf16(a, bf, acc, 0, 0, 0);
  }
  int orow = rt * 16 + (l >> 4) * 4;
  int ocol = ct * 16 + (l & 15);
#pragma unroll
  for (int r = 0; r < 4; ++r)
    P[(size_t)(orow + r) * 256 + ocol] = f2bf(acc[r]);
}

// ---- B: fused G = P.X^T tile GEMM + exp-sum buckets.
// Grid: (96 row-blocks of 64, 6 t-chunks of 32). Block 256 = 4 waves, wave owns 16 rows.
__global__ __launch_bounds__(256) void k_scores(const ushort* __restrict__ P,
                                                const ushort* __restrict__ X,
                                                float* __restrict__ sum0,
                                                float* __restrict__ tail) {
  __shared__ ushort xt[8192];  // 16KB: one t-tile (32 cols x 256 K) = 1024 short8 chunks
  int tid = threadIdx.x;
  int w = tid >> 6, l = tid & 63;
  int rowbase = blockIdx.x * 64 + w * 16;
  int tbase = blockIdx.y * 32;

  // Hoist A fragments: lane l -> row rowbase+(l&15), k-chunk (l>>4)*8, 8 K-steps
  short8 a[8];
  {
    const short8* pp = (const short8*)(P + (size_t)(rowbase + (l & 15)) * 256);
    int kh = l >> 4;
#pragma unroll
    for (int kk = 0; kk < 8; ++kk) a[kk] = pp[kk * 4 + kh];
  }

  // Staging: thread tid stages 4 of the 1024 short8 chunks of the tile.
  // chunk (kslot, col): LDS idx = kslot*32 + col, kslot = ks0 + q*8, q=0..3.
  // global: X[(t*32+col)] row, short8 index kslot within the row.
  int col = tid & 31, ks0 = tid >> 5;  // ks0 in [0,8)
  const short8* xg = (const short8*)X;
  short8* xts = (short8*)xt;

  float sacc[4] = {0.f, 0.f, 0.f, 0.f};
  short8 stg[4];
  {
    const short8* rowp = xg + ((size_t)tbase * 32 + col) * 32;
#pragma unroll
    for (int q = 0; q < 4; ++q) stg[q] = rowp[ks0 + q * 8];
  }

  for (int t_l = 0; t_l < 32; ++t_l) {
    int t = tbase + t_l;
#pragma unroll
    for (int q = 0; q < 4; ++q) xts[(ks0 + q * 8) * 32 + col] = stg[q];
    __syncthreads();
    if (t_l + 1 < 32) {
      const short8* rowp = xg + ((size_t)(t + 1) * 32 + col) * 32;
#pragma unroll
      for (int q = 0; q < 4; ++q) stg[q] = rowp[ks0 + q * 8];
    }

    f32x4 acc0 = {0.f, 0.f, 0.f, 0.f}, acc1 = {0.f, 0.f, 0.f, 0.f};
    int kh = l >> 4, cl = l & 15;
#pragma unroll
    for (int kk = 0; kk < 8; ++kk) {
      short8 b0 = xts[(kk * 4 + kh) * 32 + cl];
      short8 b1 = xts[(kk * 4 + kh) * 32 + 16 + cl];
      acc0 = __builtin_amdgcn_mfma_f32_16x16x32_bf16(a[kk], b0, acc0, 0, 0, 0);
      acc1 = __builtin_amdgcn_mfma_f32_16x16x32_bf16(a[kk], b1, acc1, 0, 0, 0);
    }
    __syncthreads();

    if (t < TAIL0) {
#pragma unroll
      for (int r = 0; r < 4; ++r)
        sacc[r] += __expf(acc0[r] - 64.f) + __expf(acc1[r] - 64.f);
    } else {
#pragma unroll
      for (int r = 0; r < 4; ++r) {
        float v = __expf(acc0[r] - 64.f) + __expf(acc1[r] - 64.f);
        v += __shfl_xor(v, 1); v += __shfl_xor(v, 2);
        v += __shfl_xor(v, 4); v += __shfl_xor(v, 8);
        if ((l & 15) == 0)
          tail[(size_t)(t - TAIL0) * NROW + rowbase + (l >> 4) * 4 + r] = v;
      }
    }
  }
#pragma unroll
  for (int r = 0; r < 4; ++r) {
    float v = sacc[r];
    v += __shfl_xor(v, 1); v += __shfl_xor(v, 2);
    v += __shfl_xor(v, 4); v += __shfl_xor(v, 8);
    if ((l & 15) == 0)
      atomicAdd(&sum0[rowbase + (l >> 4) * 4 + r], v);
  }
}

// ---- C: positives pos[u][s] = dot(P[u], X[(urow-s)*32+b]), one wave per row
__global__ void k_pos(const ushort* __restrict__ P, const ushort* __restrict__ X,
                      float* __restrict__ pos) {
  int w = threadIdx.x >> 6, l = threadIdx.x & 63;
  int u = blockIdx.x * 4 + w;
  int b = u / 192, urow = u % 192;
  ushort4 pu = ((const ushort4*)(P + (size_t)u * 256))[l];
  float p0 = b2f(pu.x), p1 = b2f(pu.y), p2 = b2f(pu.z), p3 = b2f(pu.w);
  int smax = urow < 11 ? urow : 11;
  for (int s = 0; s <= smax; ++s) {
    int c = (urow - s) * 32 + b;
    ushort4 xc = ((const ushort4*)(X + (size_t)c * 256))[l];
    float d = p0 * b2f(xc.x) + p1 * b2f(xc.y) + p2 * b2f(xc.z) + p3 * b2f(xc.w);
    d += __shfl_xor(d, 1);  d += __shfl_xor(d, 2);  d += __shfl_xor(d, 4);
    d += __shfl_xor(d, 8);  d += __shfl_xor(d, 16); d += __shfl_xor(d, 32);
    if (l == 0) pos[u * 12 + s] = d;
  }
}

// ---- D: per-row loss terms + global reduce
__global__ void k_loss(const float* __restrict__ sum0, const float* __restrict__ tail,
                       const float* __restrict__ pos, float* __restrict__ acc) {
  int u = blockIdx.x * 256 + threadIdx.x;
  int urow = u % 192;
  int smax = urow < 11 ? urow : 11;
  float denom = sum0[u];
  float local = 0.f;
  for (int s = 11; s >= 0; --s) {
    if (s < 11) denom += tail[(size_t)(10 - s) * NROW + u];
    if (s <= smax)
      local += pos[u * 12 + s] - 64.f - __logf(denom) + __logf(32.f * (float)(192 - s));
  }
  float v = local;
  v += __shfl_xor(v, 1);  v += __shfl_xor(v, 2);  v += __shfl_xor(v, 4);
  v += __shfl_xor(v, 8);  v += __shfl_xor(v, 16); v += __shfl_xor(v, 32);
  __shared__ float red[4];
  if ((threadIdx.x & 63) == 0) red[threadIdx.x >> 6] = v;
  __syncthreads();
  if (threadIdx.x == 0) atomicAdd(acc, red[0] + red[1] + red[2] + red[3]);
}

__global__ void k_final(const float* __restrict__ acc, float* __restrict__ out) {
  if (threadIdx.x == 0) out[0] = -acc[0] * (1.0f / NTERMS);
}

extern "C" void kernel_launch(void* const* d_in, const int* in_sizes, int n_in,
                              void* d_out, int out_size, void* d_ws, size_t ws_size,
                              hipStream_t stream) {
  const float* emb = (const float*)d_in[0];
  const float* ctx = (const float*)d_in[1];
  const float* W   = (const float*)d_in[2];
  char* ws = (char*)d_ws;
  // ws layout (all 256-aligned):
  ushort* P    = (ushort*)(ws + 0);         // 6144x256 bf16 = 3,145,728
  ushort* X    = (ushort*)(ws + 3145728);   // 6144x256 bf16 = 3,145,728
  ushort* Wt   = (ushort*)(ws + 6291456);   // 256x256 bf16  =   131,072
  float*  sum0 = (float*)(ws + 6422528);    // 6144 f32      =    24,576
  float*  acc  = (float*)(ws + 6447104);    // 1 f32
  float*  tail = (float*)(ws + 6447360);    // 11x6144 f32   =   270,336
  float*  pos  = (float*)(ws + 6717696);    // 6144x12 f32   =   294,912

  hipMemsetAsync(sum0, 0, 24580, stream);   // sum0 + acc

  k_castW<<<256, 256, 0, stream>>>(W, Wt);
  k_castX<<<6144, 64, 0, stream>>>(ctx, X);
  k_proj<<<1536, 256, 0, stream>>>(emb, Wt, P);
  k_scores<<<dim3(96, 6), 256, 0, stream>>>(P, X, sum0, tail);
  k_pos<<<1536, 256, 0, stream>>>(P, X, pos);
  k_loss<<<24, 256, 0, stream>>>(sum0, tail, pos, acc);
  k_final<<<1, 64, 0, stream>>>(acc, (float*)d_out);
}

// Round 3
// 78.429 us; speedup vs baseline: 1.3407x; 1.3407x over previous
//
#include <hip/hip_runtime.h>
#include <hip/hip_bf16.h>

// B=32, T=256, E=C=256, MIN_CONTEXT=64, FUTURE_STEPS=12
// S0=192, NROW=6144, K=256. G = P·X^T (6144x6144), bucketed exp-sums.
// t in [181,192) are singleton tail buckets; bucket0 = t<181. N_terms=71616.

#define NROW 6144
#define TAIL0 181
#define NTERMS 71616.0f

typedef __attribute__((ext_vector_type(8))) short short8;
typedef __attribute__((ext_vector_type(4))) float f32x4;

__device__ __forceinline__ ushort f2bf(float f) {
  union { float f; uint32_t u; } v; v.f = f;
  uint32_t u = v.u;
  return (ushort)((u + 0x7FFFu + ((u >> 16) & 1u)) >> 16);
}
__device__ __forceinline__ float b2f(ushort h) {
  union { uint32_t u; float f; } v; v.u = ((uint32_t)h) << 16; return v.f;
}

// async global->LDS, 16B per lane; lds dst must be wave-uniform base
__device__ __forceinline__ void gload16(const ushort* g, ushort* l) {
  __builtin_amdgcn_global_load_lds((const __attribute__((address_space(1))) void*)g,
                                   (__attribute__((address_space(3))) void*)l, 16, 0, 0);
}

// ---- A0: W (E,C) fp32 -> Wt (C,E) bf16
__global__ void k_castW(const float* __restrict__ W, ushort* __restrict__ Wt) {
  int c = blockIdx.x, e = threadIdx.x;
  Wt[c * 256 + e] = f2bf(W[e * 256 + c]);
}

// ---- A1: contexts -> X bf16, t-major: X[t*32+j][k] = ctx[j][63+t][k]
__global__ void k_castX(const float* __restrict__ ctx, ushort* __restrict__ X) {
  int c = blockIdx.x;      // 6144
  int j = c & 31, t = c >> 5;
  const float4* src = (const float4*)(ctx + ((size_t)(j * 256 + 63 + t)) * 256);
  float4 f = src[threadIdx.x];
  ushort4 o;
  o.x = f2bf(f.x); o.y = f2bf(f.y); o.z = f2bf(f.z); o.w = f2bf(f.w);
  ((ushort4*)(X + (size_t)c * 256))[threadIdx.x] = o;
}

// ---- A2: P = emb_slice @ W. Block = 1 row-tile (16 rows), A cast once into LDS,
// 4 waves x 4 col-tiles each. XOR-swizzled LDS (chunk ^ (row&7)) -> 2-way reads.
__global__ __launch_bounds__(256) void k_proj(const float* __restrict__ emb,
                                              const ushort* __restrict__ Wt,
                                              ushort* __restrict__ P) {
  __shared__ ushort Al[16 * 256];  // 8KB
  int tid = threadIdx.x;
  int rt = blockIdx.x;             // 384 row tiles
  // stage: 1024 float4 chunks; thread does 4. cc -> row=cc>>6, f4=cc&63
#pragma unroll
  for (int q = 0; q < 4; ++q) {
    int cc = tid + q * 256;
    int rw = cc >> 6, f4 = cc & 63;
    int u = rt * 16 + rw, b = u / 192, urow = u - b * 192;
    float4 f = *(const float4*)(emb + ((size_t)(b * 256 + 64 + urow)) * 256 + f4 * 4);
    ushort4 o;
    o.x = f2bf(f.x); o.y = f2bf(f.y); o.z = f2bf(f.z); o.w = f2bf(f.w);
    int c8 = f4 >> 1;  // short8 chunk 0..31
    *(ushort4*)&Al[rw * 256 + ((c8 ^ (rw & 7)) * 8) + (f4 & 1) * 4] = o;
  }
  __syncthreads();

  int w = tid >> 6, l = tid & 63;
  int fr = l & 15, kb = l >> 4;
  // hoist A frags: af[kk] = A[row=fr][k=kk*32+kb*8 ..]
  short8 af[8];
#pragma unroll
  for (int kk = 0; kk < 8; ++kk) {
    int c8 = kk * 4 + kb;
    af[kk] = *(const short8*)&Al[fr * 256 + (c8 ^ (fr & 7)) * 8];
  }
#pragma unroll
  for (int i = 0; i < 4; ++i) {
    int ct = w * 4 + i;
    const short8* bp = (const short8*)(Wt + (size_t)(ct * 16 + fr) * 256);
    f32x4 acc = {0.f, 0.f, 0.f, 0.f};
#pragma unroll
    for (int kk = 0; kk < 8; ++kk)
      acc = __builtin_amdgcn_mfma_f32_16x16x32_bf16(af[kk], bp[kk * 4 + kb], acc, 0, 0, 0);
#pragma unroll
    for (int r = 0; r < 4; ++r)
      P[(size_t)(rt * 16 + kb * 4 + r) * 256 + ct * 16 + fr] = f2bf(acc[r]);
  }
}

// ---- B: 128x128-tile GEMM G = P·X^T fused with exp-bucket epilogue + positives.
// Grid (48,48), 256 thr = 4 waves (wr,wc), wave tile 64x64, acc[4][4].
// K-loop: 8 steps of BK=32, global_load_lds staging, 2 barriers/step.
// LDS [128][32] row-major with 2-bit XOR swizzle (slot ^ (row>>1)&3) applied via
// pre-swizzled GLOBAL source (linear LDS dest) -> 2-way (free) ds_read_b128.
__global__ __launch_bounds__(256) void k_scores(const ushort* __restrict__ P,
                                                const ushort* __restrict__ X,
                                                float* __restrict__ sum0,
                                                float* __restrict__ tail,
                                                float* __restrict__ pos) {
  __shared__ ushort Al[128 * 32];
  __shared__ ushort Bl[128 * 32];
  int tid = threadIdx.x;
  int w = tid >> 6, l = tid & 63;
  int wr = w >> 1, wc = w & 1;
  int rowbase = blockIdx.x * 128;
  int colbase = blockIdx.y * 128;

  // staging: chunk c in [0,512), c = w*128 + q*64 + l; row=c>>2, slot=c&3
  // source k-slot = slot ^ ((row>>1)&3) so linear LDS write lands swizzled
  int c0 = w * 128 + l;
  int r0 = c0 >> 2, s0 = (c0 & 3) ^ ((c0 >> 3) & 3);
  int c1 = c0 + 64;
  int r1 = c1 >> 2, s1 = (c1 & 3) ^ ((c1 >> 3) & 3);
  const ushort* gA0 = P + (size_t)(rowbase + r0) * 256 + s0 * 8;
  const ushort* gA1 = P + (size_t)(rowbase + r1) * 256 + s1 * 8;
  const ushort* gB0 = X + (size_t)(colbase + r0) * 256 + s0 * 8;
  const ushort* gB1 = X + (size_t)(colbase + r1) * 256 + s1 * 8;
  ushort* lA0 = Al + (size_t)(w * 128) * 8;   // wave-uniform bases
  ushort* lA1 = Al + (size_t)(w * 128 + 64) * 8;
  ushort* lB0 = Bl + (size_t)(w * 128) * 8;
  ushort* lB1 = Bl + (size_t)(w * 128 + 64) * 8;

  int fr = l & 15, kb = l >> 4;
  int kbs = kb ^ ((fr >> 1) & 3);  // swizzled slot for reads

  f32x4 acc[4][4];
#pragma unroll
  for (int m = 0; m < 4; ++m)
#pragma unroll
    for (int n = 0; n < 4; ++n) acc[m][n] = {0.f, 0.f, 0.f, 0.f};

  for (int kk = 0; kk < 8; ++kk) {
    gload16(gA0 + kk * 32, lA0);
    gload16(gA1 + kk * 32, lA1);
    gload16(gB0 + kk * 32, lB0);
    gload16(gB1 + kk * 32, lB1);
    __syncthreads();   // drains vmcnt (gload) for all waves

    short8 af[4], bf[4];
#pragma unroll
    for (int m = 0; m < 4; ++m)
      af[m] = *(const short8*)&Al[(wr * 64 + m * 16 + fr) * 32 + kbs * 8];
#pragma unroll
    for (int n = 0; n < 4; ++n)
      bf[n] = *(const short8*)&Bl[(wc * 64 + n * 16 + fr) * 32 + kbs * 8];
#pragma unroll
    for (int m = 0; m < 4; ++m)
#pragma unroll
      for (int n = 0; n < 4; ++n)
        acc[m][n] = __builtin_amdgcn_mfma_f32_16x16x32_bf16(af[m], bf[n], acc[m][n], 0, 0, 0);
    if (kk < 7) __syncthreads();  // protect LDS overwrite by next stage
  }

  // ---- epilogue: positives + exp bucket sums
  // C/D: row_in_frag = kb*4+r, col_in_frag = fr
  int t0g = blockIdx.y * 4 + wc * 2;  // wave covers t0g, t0g+1 (32 cols each)
#pragma unroll
  for (int m = 0; m < 4; ++m) {
    int rowg = rowbase + wr * 64 + m * 16 + kb * 4;
#pragma unroll
    for (int r = 0; r < 4; ++r) {
      int u = rowg + r;
      int b = u / 192;
      int urow = u - b * 192;
      // positives: this lane's 4 cols in this (m,r)
#pragma unroll
      for (int n = 0; n < 4; ++n) {
        int colg = colbase + wc * 64 + n * 16 + fr;
        int dt = urow - (colg >> 5);
        if ((colg & 31) == b && dt >= 0 && dt < 12)
          pos[u * 12 + dt] = acc[m][n][r];
      }
      float v0 = __expf(acc[m][0][r] - 64.f) + __expf(acc[m][1][r] - 64.f);
      float v1 = __expf(acc[m][2][r] - 64.f) + __expf(acc[m][3][r] - 64.f);
      v0 += __shfl_xor(v0, 1); v0 += __shfl_xor(v0, 2);
      v0 += __shfl_xor(v0, 4); v0 += __shfl_xor(v0, 8);
      v1 += __shfl_xor(v1, 1); v1 += __shfl_xor(v1, 2);
      v1 += __shfl_xor(v1, 4); v1 += __shfl_xor(v1, 8);
      if (fr == 0) {
        if (t0g + 1 < TAIL0) {
          atomicAdd(&sum0[u], v0 + v1);
        } else if (t0g < TAIL0) {
          atomicAdd(&sum0[u], v0);
          tail[(size_t)(t0g + 1 - TAIL0) * NROW + u] = v1;
        } else {
          tail[(size_t)(t0g - TAIL0) * NROW + u] = v0;
          tail[(size_t)(t0g + 1 - TAIL0) * NROW + u] = v1;
        }
      }
    }
  }
}

// ---- D: per-row loss terms + global reduce
__global__ void k_loss(const float* __restrict__ sum0, const float* __restrict__ tail,
                       const float* __restrict__ pos, float* __restrict__ acc) {
  int u = blockIdx.x * 256 + threadIdx.x;
  int urow = u % 192;
  int smax = urow < 11 ? urow : 11;
  float denom = sum0[u];
  float local = 0.f;
  for (int s = 11; s >= 0; --s) {
    if (s < 11) denom += tail[(size_t)(10 - s) * NROW + u];
    if (s <= smax)
      local += pos[u * 12 + s] - 64.f - __logf(denom) + __logf(32.f * (float)(192 - s));
  }
  float v = local;
  v += __shfl_xor(v, 1);  v += __shfl_xor(v, 2);  v += __shfl_xor(v, 4);
  v += __shfl_xor(v, 8);  v += __shfl_xor(v, 16); v += __shfl_xor(v, 32);
  __shared__ float red[4];
  if ((threadIdx.x & 63) == 0) red[threadIdx.x >> 6] = v;
  __syncthreads();
  if (threadIdx.x == 0) atomicAdd(acc, red[0] + red[1] + red[2] + red[3]);
}

__global__ void k_final(const float* __restrict__ acc, float* __restrict__ out) {
  if (threadIdx.x == 0) out[0] = -acc[0] * (1.0f / NTERMS);
}

extern "C" void kernel_launch(void* const* d_in, const int* in_sizes, int n_in,
                              void* d_out, int out_size, void* d_ws, size_t ws_size,
                              hipStream_t stream) {
  const float* emb = (const float*)d_in[0];
  const float* ctx = (const float*)d_in[1];
  const float* W   = (const float*)d_in[2];
  char* ws = (char*)d_ws;
  ushort* P    = (ushort*)(ws + 0);         // 6144x256 bf16 = 3,145,728
  ushort* X    = (ushort*)(ws + 3145728);   // 6144x256 bf16 = 3,145,728
  ushort* Wt   = (ushort*)(ws + 6291456);   // 256x256 bf16  =   131,072
  float*  sum0 = (float*)(ws + 6422528);    // 6144 f32
  float*  acc  = (float*)(ws + 6447104);    // 1 f32
  float*  tail = (float*)(ws + 6447360);    // 11x6144 f32
  float*  pos  = (float*)(ws + 6717696);    // 6144x12 f32

  hipMemsetAsync(sum0, 0, 24580, stream);   // sum0 + acc

  k_castW<<<256, 256, 0, stream>>>(W, Wt);
  k_castX<<<6144, 64, 0, stream>>>(ctx, X);
  k_proj<<<384, 256, 0, stream>>>(emb, Wt, P);
  k_scores<<<dim3(48, 48), 256, 0, stream>>>(P, X, sum0, tail, pos);
  k_loss<<<24, 256, 0, stream>>>(sum0, tail, pos, acc);
  k_final<<<1, 64, 0, stream>>>(acc, (float*)d_out);
}